// Round 9
// baseline (388.825 us; speedup 1.0000x reference)
//
#include <hip/hip_runtime.h>

// SpectralRewiringLayer. Factorized: h1 = relu(u[src] + v[dst]),
//   u[n] = W1[0:64]^T emb[n] + b1 + fied[n]*W1[128]
//   v[n] = W1[64:128]^T emb[n] + fied[n]*W1[129]
// R1-R8 finding: every variant delivers ~536 MB at 6-7 TB/s (the D2D
// ceiling) regardless of occupancy/pipeline depth -> R4 structure is at
// the delivered-bandwidth roofline. R9 reduces BYTES: counting-sort edges
// by src (grouping only, order irrelevant) so tiles share u rows and the
// TA coalescer collapses u-gathers to ~1-2 lines/tile. v stays random
// (irreducible). Sort: hist + unordered range-assign (1 atomic/wave) +
// scatter. edge_mlp = R4-proven depth-2 pipeline over sorted arrays,
// output scattered via seid.

#define HD 64

typedef __attribute__((ext_vector_type(8))) _Float16 half8;
typedef __attribute__((ext_vector_type(4))) _Float16 half4;
typedef __attribute__((ext_vector_type(2))) _Float16 half2v;
typedef __attribute__((ext_vector_type(2))) __fp16  fp16x2;
typedef __attribute__((ext_vector_type(8))) short  short8;
typedef __attribute__((ext_vector_type(2))) short  short2v;
typedef __attribute__((ext_vector_type(8))) float  float8;
typedef __attribute__((ext_vector_type(4))) float  f32x4;

__device__ __forceinline__ half8 relu_h8(half8 x) {
    short8 b = __builtin_bit_cast(short8, x);
    short8 m = b >> 15;
    b = b & ~m;
    return __builtin_bit_cast(half8, b);
}
__device__ __forceinline__ half2v relu_h2(half2v x) {
    short2v b = __builtin_bit_cast(short2v, x);
    short2v m = b >> 15;
    b = b & ~m;
    return __builtin_bit_cast(half2v, b);
}
__device__ __forceinline__ half2v pkrtz(float a, float b) {
    return __builtin_bit_cast(half2v, __builtin_amdgcn_cvt_pkrtz(a, b));
}
__device__ __forceinline__ float fdot2f(half2v a, half2v b, float c) {
    return __builtin_amdgcn_fdot2(__builtin_bit_cast(fp16x2, a),
                                  __builtin_bit_cast(fp16x2, b), c, false);
}

// ---------------- K1: u,v precompute, transposed MFMA GEMM ----------------
__global__ __launch_bounds__(256) void precompute_uv(
    const float* __restrict__ emb, const float* __restrict__ fied,
    const float* __restrict__ W1, const float* __restrict__ b1,
    _Float16* __restrict__ u, _Float16* __restrict__ v,
    int n_nodes, int ntiles)
{
    const int lane = threadIdx.x & 63;
    const int q = lane >> 4;
    const int c = lane & 15;
    const int wid = blockIdx.x * (blockDim.x >> 6) + (threadIdx.x >> 6);
    const int nw  = gridDim.x * (blockDim.x >> 6);

    half8 Au[4][2], Av[4][2];
    #pragma unroll
    for (int t = 0; t < 4; ++t)
        #pragma unroll
        for (int ks = 0; ks < 2; ++ks)
            #pragma unroll
            for (int j = 0; j < 8; ++j) {
                int k = ks * 32 + q * 8 + j;
                Au[t][ks][j] = (_Float16)W1[k * HD + t * 16 + c];
                Av[t][ks][j] = (_Float16)W1[(64 + k) * HD + t * 16 + c];
            }
    f32x4 b1q[4], wsq[4], wdq[4];
    #pragma unroll
    for (int t = 0; t < 4; ++t) {
        b1q[t] = *(const f32x4*)(b1 + t * 16 + q * 4);
        wsq[t] = *(const f32x4*)(W1 + 128 * HD + t * 16 + q * 4);
        wdq[t] = *(const f32x4*)(W1 + 129 * HD + t * 16 + q * 4);
    }

    for (int tile = wid; tile < ntiles; tile += nw) {
        const int n0 = tile * 16;
        const int n  = n0 + c;
        int na = n; if (na >= n_nodes) na = n_nodes - 1;
        const float* rp = emb + (size_t)na * HD + q * 8;
        float8 a0 = *(const float8*)rp;
        float8 a1 = *(const float8*)(rp + 32);
        half8 B0 = __builtin_convertvector(a0, half8);
        half8 B1 = __builtin_convertvector(a1, half8);

        f32x4 aU[4] = {}, aV[4] = {};
        #pragma unroll
        for (int t = 0; t < 4; ++t) {
            aU[t] = __builtin_amdgcn_mfma_f32_16x16x32_f16(Au[t][0], B0, aU[t], 0, 0, 0);
            aU[t] = __builtin_amdgcn_mfma_f32_16x16x32_f16(Au[t][1], B1, aU[t], 0, 0, 0);
            aV[t] = __builtin_amdgcn_mfma_f32_16x16x32_f16(Av[t][0], B0, aV[t], 0, 0, 0);
            aV[t] = __builtin_amdgcn_mfma_f32_16x16x32_f16(Av[t][1], B1, aV[t], 0, 0, 0);
        }

        const float fv = fied[na];
        const bool ok = (n < n_nodes);
        #pragma unroll
        for (int t = 0; t < 4; ++t) {
            half4 hu, hv;
            #pragma unroll
            for (int r = 0; r < 4; ++r) {
                hu[r] = (_Float16)(aU[t][r] + b1q[t][r] + fv * wsq[t][r]);
                hv[r] = (_Float16)(aV[t][r] + fv * wdq[t][r]);
            }
            if (ok) {
                *(half4*)(u + (size_t)n * HD + t * 16 + q * 4) = hu;
                *(half4*)(v + (size_t)n * HD + t * 16 + q * 4) = hv;
            }
        }
    }
}

// ---------------- sort-by-src chain (grouping only) ----------------
__global__ __launch_bounds__(256) void hist_k(
    const int* __restrict__ src, int* __restrict__ cnt, int E)
{
    int i  = blockIdx.x * blockDim.x + threadIdx.x;
    int st = gridDim.x * blockDim.x;
    for (; i < E; i += st) atomicAdd(&cnt[src[i]], 1);
}

// Unordered bin-range assignment: wave-scan of 64 counts, one atomic/wave.
__global__ __launch_bounds__(256) void assign_k(
    const int* __restrict__ cnt, int* __restrict__ curs,
    int* __restrict__ gcnt, int nn)
{
    const int lane = threadIdx.x & 63;
    const int w    = (blockIdx.x * blockDim.x + threadIdx.x) >> 6;
    const int bin  = w * 64 + lane;
    int x = (bin < nn) ? cnt[bin] : 0;
    int inc = x;
    #pragma unroll
    for (int off = 1; off < 64; off <<= 1) {
        int t = __shfl_up(inc, off, 64);
        if (lane >= off) inc += t;
    }
    int ex = inc - x;
    int base = 0;
    if (lane == 63) base = atomicAdd(gcnt, inc);
    base = __shfl(base, 63, 64);
    if (bin < nn) curs[bin] = base + ex;
}

__global__ __launch_bounds__(256) void scatter_k(
    const int* __restrict__ src, const int* __restrict__ dst,
    int* __restrict__ curs, int* __restrict__ ssrc,
    int* __restrict__ sdst, int* __restrict__ seid, int E)
{
    int i  = blockIdx.x * blockDim.x + threadIdx.x;
    int st = gridDim.x * blockDim.x;
    for (; i < E; i += st) {
        int s = src[i];
        int p = atomicAdd(&curs[s], 1);
        ssrc[p] = s;
        sdst[p] = dst[i];
        seid[p] = i;
    }
}

// ---------------- K2: per-edge MLP (layers 2+3), R4 structure ----------------
// seid != nullptr: edges are src-grouped, output scattered via seid.
__global__ __launch_bounds__(256) void edge_mlp(
    const _Float16* __restrict__ u, const _Float16* __restrict__ v,
    const int* __restrict__ src, const int* __restrict__ dst,
    const int* __restrict__ seid,
    const float* __restrict__ W2, const float* __restrict__ b2,
    const float* __restrict__ W3, const float* __restrict__ b3,
    float* __restrict__ out, int E, int ntiles)
{
    const int lane = threadIdx.x & 63;
    const int q = lane >> 4;
    const int c = lane & 15;
    const int wid = blockIdx.x * (blockDim.x >> 6) + (threadIdx.x >> 6);
    const int nw  = gridDim.x * (blockDim.x >> 6);

    half8 Af[4][2];
    #pragma unroll
    for (int t = 0; t < 4; ++t)
        #pragma unroll
        for (int ks = 0; ks < 2; ++ks)
            #pragma unroll
            for (int j = 0; j < 8; ++j) {
                int k = ks * 32 + q * 8 + j;
                Af[t][ks][j] = (_Float16)W2[k * HD + t * 16 + c];
            }
    half2v b2p[4][2], w3p[4][2];
    #pragma unroll
    for (int t = 0; t < 4; ++t) {
        int f = t * 16 + q * 4;
        b2p[t][0] = half2v{(_Float16)b2[f],     (_Float16)b2[f + 1]};
        b2p[t][1] = half2v{(_Float16)b2[f + 2], (_Float16)b2[f + 3]};
        w3p[t][0] = half2v{(_Float16)W3[f],     (_Float16)W3[f + 1]};
        w3p[t][1] = half2v{(_Float16)W3[f + 2], (_Float16)W3[f + 3]};
    }
    const float b3v = b3[0];

    auto eid = [&](int tile) {
        int t = tile; if (t >= ntiles) t = ntiles - 1;
        int e = t * 16 + c; if (e >= E) e = E - 1;
        return e;
    };
    auto ldidx = [&](int tile, int& s, int& d, int& g) {
        int e = eid(tile);
        s = src[e]; d = dst[e];
        g = seid ? seid[e] : e;
    };
    auto issue = [&](int s, int d, half8& Ua, half8& Ub, half8& Va, half8& Vb) {
        const half8* up = (const half8*)(u + (unsigned)s * HD + q * 8);
        const half8* vp = (const half8*)(v + (unsigned)d * HD + q * 8);
        Ua = up[0]; Ub = up[4]; Va = vp[0]; Vb = vp[4];
    };
    auto compute_store = [&](int tile, int g, half8 Ua, half8 Ub, half8 Va, half8 Vb) {
        half8 B0 = relu_h8(Ua + Va);
        half8 B1 = relu_h8(Ub + Vb);
        float p = 0.f;
        #pragma unroll
        for (int t = 0; t < 4; ++t) {
            f32x4 acc = {};
            acc = __builtin_amdgcn_mfma_f32_16x16x32_f16(Af[t][0], B0, acc, 0, 0, 0);
            acc = __builtin_amdgcn_mfma_f32_16x16x32_f16(Af[t][1], B1, acc, 0, 0, 0);
            half2v h0 = relu_h2(pkrtz(acc[0], acc[1]) + b2p[t][0]);
            half2v h1 = relu_h2(pkrtz(acc[2], acc[3]) + b2p[t][1]);
            p = fdot2f(h0, w3p[t][0], p);
            p = fdot2f(h1, w3p[t][1], p);
        }
        p += __shfl_xor(p, 16, 64);
        p += __shfl_xor(p, 32, 64);
        if (q == 0) {
            int e = tile * 16 + c;
            if (e < E) out[g] = p + b3v;
        }
    };

    const int stride = nw * 2;
    const int base0  = wid * 2;
    if (base0 >= ntiles) return;

    // ---- prologue ----
    int s0, d0, g0, s1, d1, g1;
    ldidx(base0, s0, d0, g0);
    ldidx(base0 + 1, s1, d1, g1);
    half8 U0a, U0b, V0a, V0b, U1a, U1b, V1a, V1b;
    issue(s0, d0, U0a, U0b, V0a, V0b);
    issue(s1, d1, U1a, U1b, V1a, V1b);
    // idx_cur: indices for refills issued in the NEXT loop body (one-ahead:
    // vmcnt retires oldest-first, so refill addresses never wait on young ops)
    int sc0, dc0, gc0, sc1, dc1, gc1;
    ldidx(base0 + stride,     sc0, dc0, gc0);
    ldidx(base0 + stride + 1, sc1, dc1, gc1);

    for (int base = base0; base < ntiles; base += stride) {
        int sn0, dn0, gn0, sn1, dn1, gn1;
        ldidx(base + 2 * stride,     sn0, dn0, gn0);
        ldidx(base + 2 * stride + 1, sn1, dn1, gn1);

        compute_store(base, g0, U0a, U0b, V0a, V0b);
        issue(sc0, dc0, U0a, U0b, V0a, V0b);
        g0 = gc0;
        compute_store(base + 1, g1, U1a, U1b, V1a, V1b);
        issue(sc1, dc1, U1a, U1b, V1a, V1b);
        g1 = gc1;

        sc0 = sn0; dc0 = dn0; gc0 = gn0;
        sc1 = sn1; dc1 = dn1; gc1 = gn1;
    }
}

extern "C" void kernel_launch(void* const* d_in, const int* in_sizes, int n_in,
                              void* d_out, int out_size, void* d_ws, size_t ws_size,
                              hipStream_t stream) {
    const float* emb  = (const float*)d_in[0];
    const float* fied = (const float*)d_in[1];
    const float* W1   = (const float*)d_in[2];
    const float* b1   = (const float*)d_in[3];
    const float* W2   = (const float*)d_in[4];
    const float* b2   = (const float*)d_in[5];
    const float* W3   = (const float*)d_in[6];
    const float* b3   = (const float*)d_in[7];
    const int*   eidx = (const int*)d_in[8];

    const int nn = in_sizes[1];
    const int E  = in_sizes[8] / 2;
    const int* srcp = eidx;
    const int* dstp = eidx + E;

    // ws layout
    char* w = (char*)d_ws;
    _Float16* u = (_Float16*)w;                       w += (size_t)nn * HD * 2;
    _Float16* v = (_Float16*)w;                       w += (size_t)nn * HD * 2;
    size_t base_need = (size_t)(w - (char*)d_ws);
    int* cnt  = (int*)w;                              w += (size_t)nn * 4;
    int* curs = (int*)w;                              w += (size_t)nn * 4;
    int* gcnt = (int*)w;                              w += 64;
    int* ssrc = (int*)w;                              w += (size_t)E * 4;
    int* sdst = (int*)w;                              w += (size_t)E * 4;
    int* sid  = (int*)w;                              w += (size_t)E * 4;
    const bool do_sort = ((size_t)(w - (char*)d_ws) <= ws_size);
    (void)base_need;

    const int ntilesN = (nn + 15) / 16;
    precompute_uv<<<1024, 256, 0, stream>>>(emb, fied, W1, b1, u, v, nn, ntilesN);

    const int ntilesE = (E + 15) / 16;
    if (do_sort) {
        hipMemsetAsync(cnt, 0, (size_t)nn * 4, stream);
        hipMemsetAsync(gcnt, 0, 4, stream);
        hist_k<<<2048, 256, 0, stream>>>(srcp, cnt, E);
        const int nwaves = (nn + 63) / 64;
        assign_k<<<(nwaves + 3) / 4, 256, 0, stream>>>(cnt, curs, gcnt, nn);
        scatter_k<<<2048, 256, 0, stream>>>(srcp, dstp, curs, ssrc, sdst, sid, E);
        edge_mlp<<<2048, 256, 0, stream>>>(u, v, ssrc, sdst, sid, W2, b2, W3, b3,
                                           (float*)d_out, E, ntilesE);
    } else {
        edge_mlp<<<2048, 256, 0, stream>>>(u, v, srcp, dstp, nullptr, W2, b2, W3, b3,
                                           (float*)d_out, E, ntilesE);
    }
}